// Round 2
// baseline (5323.589 us; speedup 1.0000x reference)
//
#include <hip/hip_runtime.h>
#include <math.h>

#define NODE_DIM 32
#define EDGE_DIM 16
#define ZDIM 80

__device__ __forceinline__ float fast_sigmoid(float v) {
    return __builtin_amdgcn_rcpf(1.0f + __expf(-v));
}

__device__ __forceinline__ float fast_softplus(float v) {
    // log1p(exp(v)), stable: max(v,0) + log(1 + exp(-|v|))
    float t = __expf(-fabsf(v));
    return fmaxf(v, 0.0f) + __logf(1.0f + t);
}

__global__ __launch_bounds__(256) void edge_kernel(
    const float* __restrict__ x,
    const int*   __restrict__ ei,
    const float* __restrict__ ea,
    const float* __restrict__ ew,
    const float* __restrict__ Wf,
    const float* __restrict__ bf,
    const float* __restrict__ Ws,
    const float* __restrict__ bs,
    float* __restrict__ agg,
    float* __restrict__ out_ei,   // NOTE: harness reads whole d_out as f32 -> write float(int)
    float* __restrict__ out_ea,
    float* __restrict__ out_ew,
    int E)
{
    const int e = blockIdx.x * blockDim.x + threadIdx.x;
    if (e >= E) return;

    const int src = ei[e];
    const int dst = ei[E + e];
    // passthrough: edge_index, as float values (whole output buffer is read as f32)
    out_ei[e]     = (float)src;
    out_ei[E + e] = (float)dst;

    float accf[NODE_DIM], accs[NODE_DIM];
    #pragma unroll
    for (int j = 0; j < NODE_DIM; ++j) {
        accf[j] = bf[j];   // uniform -> scalar load
        accs[j] = bs[j];
    }

    // segment 1: z[0..31] = x[dst]
    const float4* xd = (const float4*)(x + (size_t)dst * NODE_DIM);
    #pragma unroll
    for (int i = 0; i < 8; ++i) {
        float4 v = xd[i];
        float zz[4] = {v.x, v.y, v.z, v.w};
        #pragma unroll
        for (int t = 0; t < 4; ++t) {
            const int k = 4 * i + t;
            #pragma unroll
            for (int j = 0; j < NODE_DIM; ++j) {
                accf[j] = fmaf(zz[t], Wf[k * NODE_DIM + j], accf[j]);
                accs[j] = fmaf(zz[t], Ws[k * NODE_DIM + j], accs[j]);
            }
        }
    }

    // segment 2: z[32..63] = x[src]
    const float4* xs = (const float4*)(x + (size_t)src * NODE_DIM);
    #pragma unroll
    for (int i = 0; i < 8; ++i) {
        float4 v = xs[i];
        float zz[4] = {v.x, v.y, v.z, v.w};
        #pragma unroll
        for (int t = 0; t < 4; ++t) {
            const int k = 32 + 4 * i + t;
            #pragma unroll
            for (int j = 0; j < NODE_DIM; ++j) {
                accf[j] = fmaf(zz[t], Wf[k * NODE_DIM + j], accf[j]);
                accs[j] = fmaf(zz[t], Ws[k * NODE_DIM + j], accs[j]);
            }
        }
    }

    // segment 3: z[64..79] = edge_attr[e], fused passthrough write
    const float4* eap = (const float4*)(ea + (size_t)e * EDGE_DIM);
    float4*       oea = (float4*)(out_ea + (size_t)e * EDGE_DIM);
    #pragma unroll
    for (int i = 0; i < 4; ++i) {
        float4 v = eap[i];
        oea[i] = v;
        float zz[4] = {v.x, v.y, v.z, v.w};
        #pragma unroll
        for (int t = 0; t < 4; ++t) {
            const int k = 64 + 4 * i + t;
            #pragma unroll
            for (int j = 0; j < NODE_DIM; ++j) {
                accf[j] = fmaf(zz[t], Wf[k * NODE_DIM + j], accf[j]);
                accs[j] = fmaf(zz[t], Ws[k * NODE_DIM + j], accs[j]);
            }
        }
    }

    const float w = ew[e];
    out_ew[e] = w;   // passthrough: edge_weight

    float* aggp = agg + (size_t)dst * NODE_DIM;
    #pragma unroll
    for (int j = 0; j < NODE_DIM; ++j) {
        float g = fast_sigmoid(accf[j]);
        float v = fast_softplus(accs[j]);
        unsafeAtomicAdd(&aggp[j], w * g * v);
    }
}

__global__ __launch_bounds__(256) void node_kernel(
    const float* __restrict__ x,
    const float* __restrict__ agg,
    const float* __restrict__ ln_g,
    const float* __restrict__ ln_b,
    const float* __restrict__ W,
    const float* __restrict__ b,
    float* __restrict__ out,
    int N)
{
    const int n = blockIdx.x * blockDim.x + threadIdx.x;
    if (n >= N) return;

    float xr[NODE_DIM], h[NODE_DIM];
    const float4* xp = (const float4*)(x   + (size_t)n * NODE_DIM);
    const float4* ap = (const float4*)(agg + (size_t)n * NODE_DIM);

    float s = 0.0f, ss = 0.0f;
    #pragma unroll
    for (int i = 0; i < 8; ++i) {
        float4 xv = xp[i];
        float4 av = ap[i];
        float hv0 = xv.x + av.x, hv1 = xv.y + av.y, hv2 = xv.z + av.z, hv3 = xv.w + av.w;
        xr[4*i+0] = xv.x; xr[4*i+1] = xv.y; xr[4*i+2] = xv.z; xr[4*i+3] = xv.w;
        h[4*i+0] = hv0; h[4*i+1] = hv1; h[4*i+2] = hv2; h[4*i+3] = hv3;
        s  += hv0 + hv1 + hv2 + hv3;
        ss += hv0*hv0 + hv1*hv1 + hv2*hv2 + hv3*hv3;
    }

    const float mu  = s * (1.0f / NODE_DIM);
    float var = ss * (1.0f / NODE_DIM) - mu * mu;
    var = fmaxf(var, 0.0f);
    const float rstd = __builtin_amdgcn_rsqf(var + 1e-5f);

    float acc[NODE_DIM];
    #pragma unroll
    for (int j = 0; j < NODE_DIM; ++j) acc[j] = b[j] + xr[j];

    #pragma unroll
    for (int k = 0; k < NODE_DIM; ++k) {
        float hn = (h[k] - mu) * rstd * ln_g[k] + ln_b[k];
        #pragma unroll
        for (int j = 0; j < NODE_DIM; ++j) {
            acc[j] = fmaf(hn, W[k * NODE_DIM + j], acc[j]);
        }
    }

    float4* op = (float4*)(out + (size_t)n * NODE_DIM);
    #pragma unroll
    for (int i = 0; i < 8; ++i) {
        float4 o;
        float a0 = acc[4*i+0], a1 = acc[4*i+1], a2 = acc[4*i+2], a3 = acc[4*i+3];
        o.x = (a0 > 0.0f) ? a0 : (__expf(a0) - 1.0f);
        o.y = (a1 > 0.0f) ? a1 : (__expf(a1) - 1.0f);
        o.z = (a2 > 0.0f) ? a2 : (__expf(a2) - 1.0f);
        o.w = (a3 > 0.0f) ? a3 : (__expf(a3) - 1.0f);
        op[i] = o;
    }
}

extern "C" void kernel_launch(void* const* d_in, const int* in_sizes, int n_in,
                              void* d_out, int out_size, void* d_ws, size_t ws_size,
                              hipStream_t stream)
{
    const float* x   = (const float*)d_in[0];
    const int*   ei  = (const int*)  d_in[1];
    const float* ea  = (const float*)d_in[2];
    const float* ew  = (const float*)d_in[3];
    const float* Wf  = (const float*)d_in[4];
    const float* bf  = (const float*)d_in[5];
    const float* Ws  = (const float*)d_in[6];
    const float* bs  = (const float*)d_in[7];
    const float* lg  = (const float*)d_in[8];
    const float* lb  = (const float*)d_in[9];
    const float* W   = (const float*)d_in[10];
    const float* b   = (const float*)d_in[11];

    const int E = in_sizes[3];              // edge_weight count = N_EDGES
    const int N = in_sizes[0] / NODE_DIM;   // N_NODES

    float* out    = (float*)d_out;
    float* out_x  = out;
    float* out_ei = out + (size_t)N * NODE_DIM;
    float* out_ea = out + (size_t)N * NODE_DIM + 2 * (size_t)E;
    float* out_ew = out_ea + (size_t)E * EDGE_DIM;

    float* agg = (float*)d_ws;
    hipMemsetAsync(agg, 0, (size_t)N * NODE_DIM * sizeof(float), stream);

    dim3 eb(256), eg((E + 255) / 256);
    edge_kernel<<<eg, eb, 0, stream>>>(x, ei, ea, ew, Wf, bf, Ws, bs,
                                       agg, out_ei, out_ea, out_ew, E);

    dim3 nb(256), ng((N + 255) / 256);
    node_kernel<<<ng, nb, 0, stream>>>(x, agg, lg, lb, W, b, out_x, N);
}

// Round 3
// 563.768 us; speedup vs baseline: 9.4429x; 9.4429x over previous
//
#include <hip/hip_runtime.h>
#include <math.h>

#define NODE_DIM 32
#define EDGE_DIM 16
#define ZDIM 80
#define EBLK 256   // edges per block

__device__ __forceinline__ float fast_sigmoid(float v) {
    return __builtin_amdgcn_rcpf(1.0f + __expf(-v));
}

__device__ __forceinline__ float fast_softplus(float v) {
    // log1p(exp(v)), stable: max(v,0) + log(1 + exp(-|v|))
    float t = __expf(-fabsf(v));
    return fmaxf(v, 0.0f) + __logf(1.0f + t);
}

__global__ __launch_bounds__(EBLK) void edge_kernel(
    const float* __restrict__ x,
    const int*   __restrict__ ei,
    const float* __restrict__ ea,
    const float* __restrict__ ew,
    const float* __restrict__ Wf,
    const float* __restrict__ bf,
    const float* __restrict__ Ws,
    const float* __restrict__ bs,
    float* __restrict__ agg,
    float* __restrict__ out_ei,   // harness reads whole d_out as f32 -> write float(int)
    float* __restrict__ out_ea,
    float* __restrict__ out_ew,
    int E)
{
    __shared__ float smsg[EBLK][NODE_DIM + 1];  // +1 pad: conflict-free both phases
    __shared__ int   sdst[EBLK];

    const int e = blockIdx.x * EBLK + threadIdx.x;
    const bool valid = (e < E);

    if (valid) {
        const int src = ei[e];
        const int dst = ei[E + e];
        sdst[threadIdx.x] = dst;
        out_ei[e]     = (float)src;
        out_ei[E + e] = (float)dst;

        float accf[NODE_DIM], accs[NODE_DIM];
        #pragma unroll
        for (int j = 0; j < NODE_DIM; ++j) {
            accf[j] = bf[j];   // uniform -> scalar load
            accs[j] = bs[j];
        }

        // segment 1: z[0..31] = x[dst]
        const float4* xd = (const float4*)(x + (size_t)dst * NODE_DIM);
        #pragma unroll
        for (int i = 0; i < 8; ++i) {
            float4 v = xd[i];
            float zz[4] = {v.x, v.y, v.z, v.w};
            #pragma unroll
            for (int t = 0; t < 4; ++t) {
                const int k = 4 * i + t;
                #pragma unroll
                for (int j = 0; j < NODE_DIM; ++j) {
                    accf[j] = fmaf(zz[t], Wf[k * NODE_DIM + j], accf[j]);
                    accs[j] = fmaf(zz[t], Ws[k * NODE_DIM + j], accs[j]);
                }
            }
        }

        // segment 2: z[32..63] = x[src]
        const float4* xs = (const float4*)(x + (size_t)src * NODE_DIM);
        #pragma unroll
        for (int i = 0; i < 8; ++i) {
            float4 v = xs[i];
            float zz[4] = {v.x, v.y, v.z, v.w};
            #pragma unroll
            for (int t = 0; t < 4; ++t) {
                const int k = 32 + 4 * i + t;
                #pragma unroll
                for (int j = 0; j < NODE_DIM; ++j) {
                    accf[j] = fmaf(zz[t], Wf[k * NODE_DIM + j], accf[j]);
                    accs[j] = fmaf(zz[t], Ws[k * NODE_DIM + j], accs[j]);
                }
            }
        }

        // segment 3: z[64..79] = edge_attr[e], fused passthrough write
        const float4* eap = (const float4*)(ea + (size_t)e * EDGE_DIM);
        float4*       oea = (float4*)(out_ea + (size_t)e * EDGE_DIM);
        #pragma unroll
        for (int i = 0; i < 4; ++i) {
            float4 v = eap[i];
            oea[i] = v;
            float zz[4] = {v.x, v.y, v.z, v.w};
            #pragma unroll
            for (int t = 0; t < 4; ++t) {
                const int k = 64 + 4 * i + t;
                #pragma unroll
                for (int j = 0; j < NODE_DIM; ++j) {
                    accf[j] = fmaf(zz[t], Wf[k * NODE_DIM + j], accf[j]);
                    accs[j] = fmaf(zz[t], Ws[k * NODE_DIM + j], accs[j]);
                }
            }
        }

        const float w = ew[e];
        out_ew[e] = w;   // passthrough

        #pragma unroll
        for (int j = 0; j < NODE_DIM; ++j) {
            float g = fast_sigmoid(accf[j]);
            float v = fast_softplus(accs[j]);
            smsg[threadIdx.x][j] = w * g * v;
        }
    } else {
        sdst[threadIdx.x] = -1;
    }

    __syncthreads();

    // Transposed, coalesced scatter: lanes 0..31 cover one edge's 32 floats
    // (contiguous 128B), lanes 32..63 the next edge. 32 atomic instrs/wave,
    // each touching 4 cache lines instead of 64.
    const int wave = threadIdx.x >> 6;   // 0..3
    const int lane = threadIdx.x & 63;
    const int sub  = lane >> 5;          // 0 or 1
    const int j    = lane & 31;

    #pragma unroll
    for (int i = 0; i < 32; ++i) {
        const int el = (wave << 6) + (i << 1) + sub;  // edge slot within block
        const int d  = sdst[el];
        if (d >= 0) {
            unsafeAtomicAdd(&agg[(size_t)d * NODE_DIM + j], smsg[el][j]);
        }
    }
}

__global__ __launch_bounds__(256) void node_kernel(
    const float* __restrict__ x,
    const float* __restrict__ agg,
    const float* __restrict__ ln_g,
    const float* __restrict__ ln_b,
    const float* __restrict__ W,
    const float* __restrict__ b,
    float* __restrict__ out,
    int N)
{
    const int n = blockIdx.x * blockDim.x + threadIdx.x;
    if (n >= N) return;

    float xr[NODE_DIM], h[NODE_DIM];
    const float4* xp = (const float4*)(x   + (size_t)n * NODE_DIM);
    const float4* ap = (const float4*)(agg + (size_t)n * NODE_DIM);

    float s = 0.0f, ss = 0.0f;
    #pragma unroll
    for (int i = 0; i < 8; ++i) {
        float4 xv = xp[i];
        float4 av = ap[i];
        float hv0 = xv.x + av.x, hv1 = xv.y + av.y, hv2 = xv.z + av.z, hv3 = xv.w + av.w;
        xr[4*i+0] = xv.x; xr[4*i+1] = xv.y; xr[4*i+2] = xv.z; xr[4*i+3] = xv.w;
        h[4*i+0] = hv0; h[4*i+1] = hv1; h[4*i+2] = hv2; h[4*i+3] = hv3;
        s  += hv0 + hv1 + hv2 + hv3;
        ss += hv0*hv0 + hv1*hv1 + hv2*hv2 + hv3*hv3;
    }

    const float mu  = s * (1.0f / NODE_DIM);
    float var = ss * (1.0f / NODE_DIM) - mu * mu;
    var = fmaxf(var, 0.0f);
    const float rstd = __builtin_amdgcn_rsqf(var + 1e-5f);

    float acc[NODE_DIM];
    #pragma unroll
    for (int j = 0; j < NODE_DIM; ++j) acc[j] = b[j] + xr[j];

    #pragma unroll
    for (int k = 0; k < NODE_DIM; ++k) {
        float hn = (h[k] - mu) * rstd * ln_g[k] + ln_b[k];
        #pragma unroll
        for (int j = 0; j < NODE_DIM; ++j) {
            acc[j] = fmaf(hn, W[k * NODE_DIM + j], acc[j]);
        }
    }

    float4* op = (float4*)(out + (size_t)n * NODE_DIM);
    #pragma unroll
    for (int i = 0; i < 8; ++i) {
        float4 o;
        float a0 = acc[4*i+0], a1 = acc[4*i+1], a2 = acc[4*i+2], a3 = acc[4*i+3];
        o.x = (a0 > 0.0f) ? a0 : (__expf(a0) - 1.0f);
        o.y = (a1 > 0.0f) ? a1 : (__expf(a1) - 1.0f);
        o.z = (a2 > 0.0f) ? a2 : (__expf(a2) - 1.0f);
        o.w = (a3 > 0.0f) ? a3 : (__expf(a3) - 1.0f);
        op[i] = o;
    }
}

extern "C" void kernel_launch(void* const* d_in, const int* in_sizes, int n_in,
                              void* d_out, int out_size, void* d_ws, size_t ws_size,
                              hipStream_t stream)
{
    const float* x   = (const float*)d_in[0];
    const int*   ei  = (const int*)  d_in[1];
    const float* ea  = (const float*)d_in[2];
    const float* ew  = (const float*)d_in[3];
    const float* Wf  = (const float*)d_in[4];
    const float* bf  = (const float*)d_in[5];
    const float* Ws  = (const float*)d_in[6];
    const float* bs  = (const float*)d_in[7];
    const float* lg  = (const float*)d_in[8];
    const float* lb  = (const float*)d_in[9];
    const float* W   = (const float*)d_in[10];
    const float* b   = (const float*)d_in[11];

    const int E = in_sizes[3];              // N_EDGES
    const int N = in_sizes[0] / NODE_DIM;   // N_NODES

    float* out    = (float*)d_out;
    float* out_x  = out;
    float* out_ei = out + (size_t)N * NODE_DIM;
    float* out_ea = out + (size_t)N * NODE_DIM + 2 * (size_t)E;
    float* out_ew = out_ea + (size_t)E * EDGE_DIM;

    float* agg = (float*)d_ws;
    hipMemsetAsync(agg, 0, (size_t)N * NODE_DIM * sizeof(float), stream);

    dim3 eb(EBLK), eg((E + EBLK - 1) / EBLK);
    edge_kernel<<<eg, eb, 0, stream>>>(x, ei, ea, ew, Wf, bf, Ws, bs,
                                       agg, out_ei, out_ea, out_ew, E);

    dim3 nb(256), ng((N + 255) / 256);
    node_kernel<<<ng, nb, 0, stream>>>(x, agg, lg, lb, W, b, out_x, N);
}

// Round 4
// 382.472 us; speedup vs baseline: 13.9189x; 1.4740x over previous
//
#include <hip/hip_runtime.h>
#include <math.h>

#define NODE_DIM 32
#define EDGE_DIM 16
#define EPB 256          // edges per block-chunk
#define MAXBLK 1250      // grid-stride block count (3.2M/256/1250 = 10 chunks each)

typedef __attribute__((ext_vector_type(8))) short bf16x8;
typedef __attribute__((ext_vector_type(4))) float f32x4;

__device__ __forceinline__ short f2bf(float f) {
    union { float f; unsigned u; } v; v.f = f;
    unsigned r = v.u + 0x7FFFu + ((v.u >> 16) & 1u);   // round-nearest-even
    return (short)(r >> 16);
}

__device__ __forceinline__ float fast_sigmoid(float v) {
    return __builtin_amdgcn_rcpf(1.0f + __expf(-v));
}
__device__ __forceinline__ float fast_softplus(float v) {
    float t = __expf(-fabsf(v));
    return fmaxf(v, 0.0f) + __logf(1.0f + t);
}

__global__ __launch_bounds__(256, 2) void edge_kernel(
    const float* __restrict__ x,
    const int*   __restrict__ ei,
    const float* __restrict__ ea,
    const float* __restrict__ ew,
    const float* __restrict__ Wf,
    const float* __restrict__ bfb,
    const float* __restrict__ Ws,
    const float* __restrict__ bsb,
    float* __restrict__ agg,
    float* __restrict__ out_ei,   // harness reads whole d_out as f32
    float* __restrict__ out_ea,
    float* __restrict__ out_ew,
    int E)
{
    __shared__ int   ssrc[EPB];
    __shared__ int   sdst[EPB];
    __shared__ float sew[EPB];

    const int tid  = threadIdx.x;
    const int lane = tid & 63;
    const int wave = tid >> 6;
    const int kg   = lane >> 4;    // 0..3: k-slice group (8 bf16 each)
    const int c16  = lane & 15;    // fragment row/col index

    // ---- B fragments: Wcomb[96][64] (cols 0-31 = Wf, 32-63 = Ws; k>=80 zero) ----
    // B layout: lane holds B[k = 32m + 8*kg + j][col = 16*ct + c16], j=0..7
    bf16x8 Bf[3][4];
    float biasv[4];
    #pragma unroll
    for (int ct = 0; ct < 4; ++ct) {
        const int cc = ct * 16 + c16;              // 0..63
        const float* Wsrc = (cc < 32) ? Wf  : Ws;
        const float* bsrc = (cc < 32) ? bfb : bsb;
        const int ccc = cc & 31;
        biasv[ct] = bsrc[ccc];
        #pragma unroll
        for (int m = 0; m < 3; ++m) {
            bf16x8 frag;
            #pragma unroll
            for (int j = 0; j < 8; ++j) {
                const int k = 32 * m + 8 * kg + j;
                const float wv = (k < 80) ? Wsrc[k * NODE_DIM + ccc] : 0.0f;
                frag[j] = f2bf(wv);
            }
            Bf[m][ct] = frag;
        }
    }

    for (int base = blockIdx.x * EPB; base < E; base += gridDim.x * EPB) {
        __syncthreads();   // previous chunk's LDS readers done before overwrite

        // ---- phase 1: passthrough + stash edge meta ----
        const int e = base + tid;
        if (e < E) {
            const int src = ei[e];
            const int dst = ei[E + e];
            const float w = ew[e];
            ssrc[tid] = src; sdst[tid] = dst; sew[tid] = w;
            out_ei[e]     = (float)src;
            out_ei[E + e] = (float)dst;
            out_ew[e]     = w;
        } else {
            ssrc[tid] = 0; sdst[tid] = -1; sew[tid] = 0.0f;
        }
        if (base + EPB <= E) {
            // fully coalesced edge_attr copy: 256 edges * 16 f = 1024 float4
            const float4* s4 = (const float4*)(ea     + (size_t)base * EDGE_DIM);
            float4*       d4 = (float4*)      (out_ea + (size_t)base * EDGE_DIM);
            #pragma unroll
            for (int t = 0; t < 4; ++t)
                d4[t * 256 + tid] = s4[t * 256 + tid];
        } else if (e < E) {
            const float4* s4 = (const float4*)(ea     + (size_t)e * EDGE_DIM);
            float4*       d4 = (float4*)      (out_ea + (size_t)e * EDGE_DIM);
            #pragma unroll
            for (int t = 0; t < 4; ++t) d4[t] = s4[t];
        }
        __syncthreads();

        // ---- phase 2: wave = 64 edges = 4 groups of 16; MFMA z@[Wf|Ws] ----
        #pragma unroll 2
        for (int g = 0; g < 4; ++g) {
            const int slotA = wave * 64 + g * 16 + c16;   // A row m = c16
            const int dstn  = max(sdst[slotA], 0);
            const int srcn  = ssrc[slotA];

            // A0: z[k=0..31]  = x[dst];  lane covers k = 8*kg .. +7
            bf16x8 a0, a1, a2;
            {
                const float4* p = (const float4*)(x + (size_t)dstn * NODE_DIM + 8 * kg);
                float4 u0 = p[0], u1 = p[1];
                a0[0]=f2bf(u0.x); a0[1]=f2bf(u0.y); a0[2]=f2bf(u0.z); a0[3]=f2bf(u0.w);
                a0[4]=f2bf(u1.x); a0[5]=f2bf(u1.y); a0[6]=f2bf(u1.z); a0[7]=f2bf(u1.w);
            }
            // A1: z[k=32..63] = x[src]
            {
                const float4* p = (const float4*)(x + (size_t)srcn * NODE_DIM + 8 * kg);
                float4 u0 = p[0], u1 = p[1];
                a1[0]=f2bf(u0.x); a1[1]=f2bf(u0.y); a1[2]=f2bf(u0.z); a1[3]=f2bf(u0.w);
                a1[4]=f2bf(u1.x); a1[5]=f2bf(u1.y); a1[6]=f2bf(u1.z); a1[7]=f2bf(u1.w);
            }
            // A2: z[k=64..95] = edge_attr (16) | zero pad
            a2[0]=0; a2[1]=0; a2[2]=0; a2[3]=0; a2[4]=0; a2[5]=0; a2[6]=0; a2[7]=0;
            if (kg < 2) {
                size_t eidx = (size_t)((base + slotA < E) ? base + slotA : E - 1);
                const float4* p = (const float4*)(ea + eidx * EDGE_DIM + 8 * kg);
                float4 u0 = p[0], u1 = p[1];
                a2[0]=f2bf(u0.x); a2[1]=f2bf(u0.y); a2[2]=f2bf(u0.z); a2[3]=f2bf(u0.w);
                a2[4]=f2bf(u1.x); a2[5]=f2bf(u1.y); a2[6]=f2bf(u1.z); a2[7]=f2bf(u1.w);
            }

            f32x4 acc0 = {biasv[0], biasv[0], biasv[0], biasv[0]};
            f32x4 acc1 = {biasv[1], biasv[1], biasv[1], biasv[1]};
            f32x4 acc2 = {biasv[2], biasv[2], biasv[2], biasv[2]};
            f32x4 acc3 = {biasv[3], biasv[3], biasv[3], biasv[3]};

            acc0 = __builtin_amdgcn_mfma_f32_16x16x32_bf16(a0, Bf[0][0], acc0, 0, 0, 0);
            acc1 = __builtin_amdgcn_mfma_f32_16x16x32_bf16(a0, Bf[0][1], acc1, 0, 0, 0);
            acc2 = __builtin_amdgcn_mfma_f32_16x16x32_bf16(a0, Bf[0][2], acc2, 0, 0, 0);
            acc3 = __builtin_amdgcn_mfma_f32_16x16x32_bf16(a0, Bf[0][3], acc3, 0, 0, 0);
            acc0 = __builtin_amdgcn_mfma_f32_16x16x32_bf16(a1, Bf[1][0], acc0, 0, 0, 0);
            acc1 = __builtin_amdgcn_mfma_f32_16x16x32_bf16(a1, Bf[1][1], acc1, 0, 0, 0);
            acc2 = __builtin_amdgcn_mfma_f32_16x16x32_bf16(a1, Bf[1][2], acc2, 0, 0, 0);
            acc3 = __builtin_amdgcn_mfma_f32_16x16x32_bf16(a1, Bf[1][3], acc3, 0, 0, 0);
            acc0 = __builtin_amdgcn_mfma_f32_16x16x32_bf16(a2, Bf[2][0], acc0, 0, 0, 0);
            acc1 = __builtin_amdgcn_mfma_f32_16x16x32_bf16(a2, Bf[2][1], acc1, 0, 0, 0);
            acc2 = __builtin_amdgcn_mfma_f32_16x16x32_bf16(a2, Bf[2][2], acc2, 0, 0, 0);
            acc3 = __builtin_amdgcn_mfma_f32_16x16x32_bf16(a2, Bf[2][3], acc3, 0, 0, 0);

            // C/D: col = c16 (+16 per ct), row = kg*4 + r  (rows = edges)
            // gate col c pairs with val col c in the SAME lane (ct0/ct2, ct1/ct3)
            const int rbase = wave * 64 + g * 16 + (kg << 2);
            #pragma unroll
            for (int r = 0; r < 4; ++r) {
                const int slot = rbase + r;
                const int d    = sdst[slot];
                const float w  = sew[slot];
                const float m0 = w * fast_sigmoid(acc0[r]) * fast_softplus(acc2[r]);
                const float m1 = w * fast_sigmoid(acc1[r]) * fast_softplus(acc3[r]);
                if (d >= 0) {
                    unsafeAtomicAdd(&agg[(size_t)d * NODE_DIM + c16],      m0);
                    unsafeAtomicAdd(&agg[(size_t)d * NODE_DIM + 16 + c16], m1);
                }
            }
        }
    }
}

__global__ __launch_bounds__(256) void node_kernel(
    const float* __restrict__ x,
    const float* __restrict__ agg,
    const float* __restrict__ ln_g,
    const float* __restrict__ ln_b,
    const float* __restrict__ W,
    const float* __restrict__ b,
    float* __restrict__ out,
    int N)
{
    const int n = blockIdx.x * blockDim.x + threadIdx.x;
    if (n >= N) return;

    float xr[NODE_DIM], h[NODE_DIM];
    const float4* xp = (const float4*)(x   + (size_t)n * NODE_DIM);
    const float4* ap = (const float4*)(agg + (size_t)n * NODE_DIM);

    float s = 0.0f, ss = 0.0f;
    #pragma unroll
    for (int i = 0; i < 8; ++i) {
        float4 xv = xp[i];
        float4 av = ap[i];
        float hv0 = xv.x + av.x, hv1 = xv.y + av.y, hv2 = xv.z + av.z, hv3 = xv.w + av.w;
        xr[4*i+0] = xv.x; xr[4*i+1] = xv.y; xr[4*i+2] = xv.z; xr[4*i+3] = xv.w;
        h[4*i+0] = hv0; h[4*i+1] = hv1; h[4*i+2] = hv2; h[4*i+3] = hv3;
        s  += hv0 + hv1 + hv2 + hv3;
        ss += hv0*hv0 + hv1*hv1 + hv2*hv2 + hv3*hv3;
    }

    const float mu  = s * (1.0f / NODE_DIM);
    float var = ss * (1.0f / NODE_DIM) - mu * mu;
    var = fmaxf(var, 0.0f);
    const float rstd = __builtin_amdgcn_rsqf(var + 1e-5f);

    float acc[NODE_DIM];
    #pragma unroll
    for (int j = 0; j < NODE_DIM; ++j) acc[j] = b[j] + xr[j];

    #pragma unroll
    for (int k = 0; k < NODE_DIM; ++k) {
        float hn = (h[k] - mu) * rstd * ln_g[k] + ln_b[k];
        #pragma unroll
        for (int j = 0; j < NODE_DIM; ++j) {
            acc[j] = fmaf(hn, W[k * NODE_DIM + j], acc[j]);
        }
    }

    float4* op = (float4*)(out + (size_t)n * NODE_DIM);
    #pragma unroll
    for (int i = 0; i < 8; ++i) {
        float4 o;
        float a0 = acc[4*i+0], a1 = acc[4*i+1], a2 = acc[4*i+2], a3 = acc[4*i+3];
        o.x = (a0 > 0.0f) ? a0 : (__expf(a0) - 1.0f);
        o.y = (a1 > 0.0f) ? a1 : (__expf(a1) - 1.0f);
        o.z = (a2 > 0.0f) ? a2 : (__expf(a2) - 1.0f);
        o.w = (a3 > 0.0f) ? a3 : (__expf(a3) - 1.0f);
        op[i] = o;
    }
}

extern "C" void kernel_launch(void* const* d_in, const int* in_sizes, int n_in,
                              void* d_out, int out_size, void* d_ws, size_t ws_size,
                              hipStream_t stream)
{
    const float* x   = (const float*)d_in[0];
    const int*   ei  = (const int*)  d_in[1];
    const float* ea  = (const float*)d_in[2];
    const float* ew  = (const float*)d_in[3];
    const float* Wf  = (const float*)d_in[4];
    const float* bf  = (const float*)d_in[5];
    const float* Ws  = (const float*)d_in[6];
    const float* bs  = (const float*)d_in[7];
    const float* lg  = (const float*)d_in[8];
    const float* lb  = (const float*)d_in[9];
    const float* W   = (const float*)d_in[10];
    const float* b   = (const float*)d_in[11];

    const int E = in_sizes[3];              // N_EDGES
    const int N = in_sizes[0] / NODE_DIM;   // N_NODES

    float* out    = (float*)d_out;
    float* out_x  = out;
    float* out_ei = out + (size_t)N * NODE_DIM;
    float* out_ea = out + (size_t)N * NODE_DIM + 2 * (size_t)E;
    float* out_ew = out_ea + (size_t)E * EDGE_DIM;

    float* agg = (float*)d_ws;
    hipMemsetAsync(agg, 0, (size_t)N * NODE_DIM * sizeof(float), stream);

    int nblk = (E + EPB - 1) / EPB;
    if (nblk > MAXBLK) nblk = MAXBLK;
    edge_kernel<<<dim3(nblk), dim3(256), 0, stream>>>(
        x, ei, ea, ew, Wf, bf, Ws, bs, agg, out_ei, out_ea, out_ew, E);

    dim3 nb(256), ng((N + 255) / 256);
    node_kernel<<<ng, nb, 0, stream>>>(x, agg, lg, lb, W, b, out_x, N);
}

// Round 5
// 371.897 us; speedup vs baseline: 14.3147x; 1.0284x over previous
//
#include <hip/hip_runtime.h>
#include <math.h>

#define NODE_DIM 32
#define EDGE_DIM 16
#define EPB 256          // edges per block-chunk
#define MAXBLK 2048      // 8 blocks/CU on 256 CUs; grid-stride over 12500 chunks

typedef __attribute__((ext_vector_type(8))) short bf16x8;
typedef __attribute__((ext_vector_type(4))) short short4v;
typedef __attribute__((ext_vector_type(4))) float f32x4;

__device__ __forceinline__ short f2bf(float f) {
    union { float f; unsigned u; } v; v.f = f;
    unsigned r = v.u + 0x7FFFu + ((v.u >> 16) & 1u);   // round-nearest-even
    return (short)(r >> 16);
}

__device__ __forceinline__ float fast_sigmoid(float v) {
    return __builtin_amdgcn_rcpf(1.0f + __expf(-v));
}
__device__ __forceinline__ float fast_softplus(float v) {
    float t = __expf(-fabsf(v));
    return fmaxf(v, 0.0f) + __logf(1.0f + t);
}

// prologue: x (f32, [N][32]) -> xb (bf16, [N][32]); one thread per 8 elems
__global__ __launch_bounds__(256) void xconv_kernel(
    const float* __restrict__ x, short* __restrict__ xb, int ngroups)
{
    const int i = blockIdx.x * 256 + threadIdx.x;
    if (i >= ngroups) return;
    const float4* p = (const float4*)x + 2 * (size_t)i;
    float4 u0 = p[0], u1 = p[1];
    bf16x8 o;
    o[0]=f2bf(u0.x); o[1]=f2bf(u0.y); o[2]=f2bf(u0.z); o[3]=f2bf(u0.w);
    o[4]=f2bf(u1.x); o[5]=f2bf(u1.y); o[6]=f2bf(u1.z); o[7]=f2bf(u1.w);
    ((bf16x8*)xb)[i] = o;
}

__global__ __launch_bounds__(256, 2) void edge_kernel(
    const short* __restrict__ xb,   // bf16 node features
    const int*   __restrict__ ei,
    const float* __restrict__ ea,
    const float* __restrict__ ew,
    const float* __restrict__ Wf,
    const float* __restrict__ bfb,
    const float* __restrict__ Ws,
    const float* __restrict__ bsb,
    float* __restrict__ agg,
    float* __restrict__ out_ei,   // harness reads whole d_out as f32
    float* __restrict__ out_ea,
    float* __restrict__ out_ew,
    int E)
{
    __shared__ int   ssrc[EPB];
    __shared__ int   sdst[EPB];
    __shared__ float sew[EPB];
    __shared__ short sea[EPB * EDGE_DIM];   // bf16 edge_attr staged in phase 1

    const int tid  = threadIdx.x;
    const int lane = tid & 63;
    const int wave = tid >> 6;
    const int kg   = lane >> 4;    // 0..3: k-slice group (8 bf16 each)
    const int c16  = lane & 15;    // fragment row/col index

    // ---- B fragments: Wcomb[96][64] (cols 0-31 = Wf, 32-63 = Ws; k>=80 zero) ----
    // lane holds B[k = 32m + 8*kg + j][col = 16*ct + c16], j=0..7
    bf16x8 Bf[3][4];
    float biasv[4];
    #pragma unroll
    for (int ct = 0; ct < 4; ++ct) {
        const int cc = ct * 16 + c16;              // 0..63
        const float* Wsrc = (cc < 32) ? Wf  : Ws;
        const float* bsrc = (cc < 32) ? bfb : bsb;
        const int ccc = cc & 31;
        biasv[ct] = bsrc[ccc];
        #pragma unroll
        for (int m = 0; m < 3; ++m) {
            bf16x8 frag;
            #pragma unroll
            for (int j = 0; j < 8; ++j) {
                const int k = 32 * m + 8 * kg + j;
                const float wv = (k < 80) ? Wsrc[k * NODE_DIM + ccc] : 0.0f;
                frag[j] = f2bf(wv);
            }
            Bf[m][ct] = frag;
        }
    }

    for (int base = blockIdx.x * EPB; base < E; base += gridDim.x * EPB) {
        __syncthreads();   // previous chunk's LDS readers done before overwrite

        // ---- phase 1: passthrough + stash edge meta + bf16 ea into LDS ----
        const int e = base + tid;
        if (e < E) {
            const int src = ei[e];
            const int dst = ei[E + e];
            const float w = ew[e];
            ssrc[tid] = src; sdst[tid] = dst; sew[tid] = w;
            out_ei[e]     = (float)src;
            out_ei[E + e] = (float)dst;
            out_ew[e]     = w;
        } else {
            ssrc[tid] = 0; sdst[tid] = -1; sew[tid] = 0.0f;
        }
        if (base + EPB <= E) {
            // fully coalesced edge_attr copy: 256 edges * 16 f = 1024 float4
            const float4* s4 = (const float4*)(ea     + (size_t)base * EDGE_DIM);
            float4*       d4 = (float4*)      (out_ea + (size_t)base * EDGE_DIM);
            #pragma unroll
            for (int t = 0; t < 4; ++t) {
                float4 v = s4[t * 256 + tid];
                d4[t * 256 + tid] = v;
                short4v sv = { f2bf(v.x), f2bf(v.y), f2bf(v.z), f2bf(v.w) };
                *(short4v*)&sea[(t * 256 + tid) * 4] = sv;
            }
        } else if (e < E) {
            const float4* s4 = (const float4*)(ea     + (size_t)e * EDGE_DIM);
            float4*       d4 = (float4*)      (out_ea + (size_t)e * EDGE_DIM);
            #pragma unroll
            for (int t = 0; t < 4; ++t) {
                float4 v = s4[t];
                d4[t] = v;
                short4v sv = { f2bf(v.x), f2bf(v.y), f2bf(v.z), f2bf(v.w) };
                *(short4v*)&sea[(tid * EDGE_DIM) + t * 4] = sv;
            }
        }
        __syncthreads();

        // ---- phase 2: wave = 64 edges = 4 groups of 16; MFMA z@[Wf|Ws] ----
        #pragma unroll 2
        for (int g = 0; g < 4; ++g) {
            const int slotA = wave * 64 + g * 16 + c16;   // A row m = c16
            const int dstn  = max(sdst[slotA], 0);
            const int srcn  = ssrc[slotA];

            // A0: z[k=0..31] = x[dst]; lane covers k = 8*kg..+7 (one 16B load)
            bf16x8 a0 = *(const bf16x8*)(xb + (size_t)dstn * NODE_DIM + 8 * kg);
            // A1: z[k=32..63] = x[src]
            bf16x8 a1 = *(const bf16x8*)(xb + (size_t)srcn * NODE_DIM + 8 * kg);
            // A2: z[k=64..95] = edge_attr (16) | zero pad, from LDS
            bf16x8 a2 = {0,0,0,0,0,0,0,0};
            if (kg < 2) {
                a2 = *(const bf16x8*)&sea[slotA * EDGE_DIM + 8 * kg];
            }

            f32x4 acc0 = {biasv[0], biasv[0], biasv[0], biasv[0]};
            f32x4 acc1 = {biasv[1], biasv[1], biasv[1], biasv[1]};
            f32x4 acc2 = {biasv[2], biasv[2], biasv[2], biasv[2]};
            f32x4 acc3 = {biasv[3], biasv[3], biasv[3], biasv[3]};

            acc0 = __builtin_amdgcn_mfma_f32_16x16x32_bf16(a0, Bf[0][0], acc0, 0, 0, 0);
            acc1 = __builtin_amdgcn_mfma_f32_16x16x32_bf16(a0, Bf[0][1], acc1, 0, 0, 0);
            acc2 = __builtin_amdgcn_mfma_f32_16x16x32_bf16(a0, Bf[0][2], acc2, 0, 0, 0);
            acc3 = __builtin_amdgcn_mfma_f32_16x16x32_bf16(a0, Bf[0][3], acc3, 0, 0, 0);
            acc0 = __builtin_amdgcn_mfma_f32_16x16x32_bf16(a1, Bf[1][0], acc0, 0, 0, 0);
            acc1 = __builtin_amdgcn_mfma_f32_16x16x32_bf16(a1, Bf[1][1], acc1, 0, 0, 0);
            acc2 = __builtin_amdgcn_mfma_f32_16x16x32_bf16(a1, Bf[1][2], acc2, 0, 0, 0);
            acc3 = __builtin_amdgcn_mfma_f32_16x16x32_bf16(a1, Bf[1][3], acc3, 0, 0, 0);
            acc0 = __builtin_amdgcn_mfma_f32_16x16x32_bf16(a2, Bf[2][0], acc0, 0, 0, 0);
            acc1 = __builtin_amdgcn_mfma_f32_16x16x32_bf16(a2, Bf[2][1], acc1, 0, 0, 0);
            acc2 = __builtin_amdgcn_mfma_f32_16x16x32_bf16(a2, Bf[2][2], acc2, 0, 0, 0);
            acc3 = __builtin_amdgcn_mfma_f32_16x16x32_bf16(a2, Bf[2][3], acc3, 0, 0, 0);

            // C/D: col = c16 (+16 per ct), row = kg*4 + r (rows = edges);
            // gate col c and val col c live in the SAME lane (ct0/ct2, ct1/ct3)
            const int rbase = wave * 64 + g * 16 + (kg << 2);
            #pragma unroll
            for (int r = 0; r < 4; ++r) {
                const int slot = rbase + r;
                const int d    = sdst[slot];
                const float w  = sew[slot];
                const float m0 = w * fast_sigmoid(acc0[r]) * fast_softplus(acc2[r]);
                const float m1 = w * fast_sigmoid(acc1[r]) * fast_softplus(acc3[r]);
                if (d >= 0) {
                    unsafeAtomicAdd(&agg[(size_t)d * NODE_DIM + c16],      m0);
                    unsafeAtomicAdd(&agg[(size_t)d * NODE_DIM + 16 + c16], m1);
                }
            }
        }
    }
}

__global__ __launch_bounds__(256) void node_kernel(
    const float* __restrict__ x,
    const float* __restrict__ agg,
    const float* __restrict__ ln_g,
    const float* __restrict__ ln_b,
    const float* __restrict__ W,
    const float* __restrict__ b,
    float* __restrict__ out,
    int N)
{
    const int n = blockIdx.x * blockDim.x + threadIdx.x;
    if (n >= N) return;

    float xr[NODE_DIM], h[NODE_DIM];
    const float4* xp = (const float4*)(x   + (size_t)n * NODE_DIM);
    const float4* ap = (const float4*)(agg + (size_t)n * NODE_DIM);

    float s = 0.0f, ss = 0.0f;
    #pragma unroll
    for (int i = 0; i < 8; ++i) {
        float4 xv = xp[i];
        float4 av = ap[i];
        float hv0 = xv.x + av.x, hv1 = xv.y + av.y, hv2 = xv.z + av.z, hv3 = xv.w + av.w;
        xr[4*i+0] = xv.x; xr[4*i+1] = xv.y; xr[4*i+2] = xv.z; xr[4*i+3] = xv.w;
        h[4*i+0] = hv0; h[4*i+1] = hv1; h[4*i+2] = hv2; h[4*i+3] = hv3;
        s  += hv0 + hv1 + hv2 + hv3;
        ss += hv0*hv0 + hv1*hv1 + hv2*hv2 + hv3*hv3;
    }

    const float mu  = s * (1.0f / NODE_DIM);
    float var = ss * (1.0f / NODE_DIM) - mu * mu;
    var = fmaxf(var, 0.0f);
    const float rstd = __builtin_amdgcn_rsqf(var + 1e-5f);

    float acc[NODE_DIM];
    #pragma unroll
    for (int j = 0; j < NODE_DIM; ++j) acc[j] = b[j] + xr[j];

    #pragma unroll
    for (int k = 0; k < NODE_DIM; ++k) {
        float hn = (h[k] - mu) * rstd * ln_g[k] + ln_b[k];
        #pragma unroll
        for (int j = 0; j < NODE_DIM; ++j) {
            acc[j] = fmaf(hn, W[k * NODE_DIM + j], acc[j]);
        }
    }

    float4* op = (float4*)(out + (size_t)n * NODE_DIM);
    #pragma unroll
    for (int i = 0; i < 8; ++i) {
        float4 o;
        float a0 = acc[4*i+0], a1 = acc[4*i+1], a2 = acc[4*i+2], a3 = acc[4*i+3];
        o.x = (a0 > 0.0f) ? a0 : (__expf(a0) - 1.0f);
        o.y = (a1 > 0.0f) ? a1 : (__expf(a1) - 1.0f);
        o.z = (a2 > 0.0f) ? a2 : (__expf(a2) - 1.0f);
        o.w = (a3 > 0.0f) ? a3 : (__expf(a3) - 1.0f);
        op[i] = o;
    }
}

extern "C" void kernel_launch(void* const* d_in, const int* in_sizes, int n_in,
                              void* d_out, int out_size, void* d_ws, size_t ws_size,
                              hipStream_t stream)
{
    const float* x   = (const float*)d_in[0];
    const int*   ei  = (const int*)  d_in[1];
    const float* ea  = (const float*)d_in[2];
    const float* ew  = (const float*)d_in[3];
    const float* Wf  = (const float*)d_in[4];
    const float* bf  = (const float*)d_in[5];
    const float* Ws  = (const float*)d_in[6];
    const float* bs  = (const float*)d_in[7];
    const float* lg  = (const float*)d_in[8];
    const float* lb  = (const float*)d_in[9];
    const float* W   = (const float*)d_in[10];
    const float* b   = (const float*)d_in[11];

    const int E = in_sizes[3];              // N_EDGES
    const int N = in_sizes[0] / NODE_DIM;   // N_NODES

    float* out    = (float*)d_out;
    float* out_x  = out;
    float* out_ei = out + (size_t)N * NODE_DIM;
    float* out_ea = out + (size_t)N * NODE_DIM + 2 * (size_t)E;
    float* out_ew = out_ea + (size_t)E * EDGE_DIM;

    // workspace layout: agg (N*32 f32 = 12.8 MB) | xb (N*32 bf16 = 6.4 MB)
    float* agg = (float*)d_ws;
    short* xbuf = (short*)((char*)d_ws + (size_t)N * NODE_DIM * sizeof(float));

    hipMemsetAsync(agg, 0, (size_t)N * NODE_DIM * sizeof(float), stream);

    const int ngroups = N * NODE_DIM / 8;
    xconv_kernel<<<dim3((ngroups + 255) / 256), dim3(256), 0, stream>>>(x, xbuf, ngroups);

    int nblk = (E + EPB - 1) / EPB;
    if (nblk > MAXBLK) nblk = MAXBLK;
    edge_kernel<<<dim3(nblk), dim3(256), 0, stream>>>(
        xbuf, ei, ea, ew, Wf, bf, Ws, bs, agg, out_ei, out_ea, out_ew, E);

    dim3 nb(256), ng((N + 255) / 256);
    node_kernel<<<ng, nb, 0, stream>>>(x, agg, lg, lb, W, b, out_x, N);
}